// Round 1
// baseline (301.786 us; speedup 1.0000x reference)
//
#include <hip/hip_runtime.h>
#include <hip/hip_bf16.h>

typedef short bf16x8 __attribute__((ext_vector_type(8)));
typedef float f32x4 __attribute__((ext_vector_type(4)));

#define MFMA16(a, b, c) __builtin_amdgcn_mfma_f32_16x16x32_bf16(a, b, c, 0, 0, 0)

#define NB 4
#define NC 256
#define NSP 4096
#define DQK 32

__device__ __forceinline__ unsigned short f2bf(float f) {
    unsigned int u = __float_as_uint(f);
    u += 0x7fffu + ((u >> 16) & 1u);
    return (unsigned short)(u >> 16);
}

// ---------------------------------------------------------------------------
// P0: weight prep. Qw[32][512] -> Qwt[512][32] fp32; Kw[32][256] -> Kwt[256][32];
//     Vw[256][512] -> bf16 (same layout).
// ---------------------------------------------------------------------------
__global__ __launch_bounds__(256) void prep_weights(
    const float* __restrict__ Qw, const float* __restrict__ Kw,
    const float* __restrict__ Vw,
    float* __restrict__ Qwt, float* __restrict__ Kwt,
    unsigned short* __restrict__ Vwbf)
{
    int i = blockIdx.x * 256 + threadIdx.x;   // 0..16383
    Qwt[i] = Qw[(i & 31) * 512 + (i >> 5)];
    if (i < 8192) Kwt[i] = Kw[(i & 31) * 256 + (i >> 5)];
    const float4* vsrc = (const float4*)(Vw + (size_t)i * 8);
    float4 a = vsrc[0], b = vsrc[1];
    int4 st;
    st.x = f2bf(a.x) | ((unsigned)f2bf(a.y) << 16);
    st.y = f2bf(a.z) | ((unsigned)f2bf(a.w) << 16);
    st.z = f2bf(b.x) | ((unsigned)f2bf(b.y) << 16);
    st.w = f2bf(b.z) | ((unsigned)f2bf(b.w) << 16);
    *(int4*)(Vwbf + (size_t)i * 8) = st;
}

// ---------------------------------------------------------------------------
// P1: q,k projections -> bf16 [B][N][32].
// Block: 256 thr = 4 wavegroups x (16 m x 4 c-slices). Cross-slice reduce via
// shfl_xor(16/32) (cs lives in lane bits 4-5).
// ---------------------------------------------------------------------------
#define ACC4(v4, i0) { a[i0] += v4.x * xv; a[i0+1] += v4.y * xv; a[i0+2] += v4.z * xv; a[i0+3] += v4.w * xv; }

__device__ __forceinline__ void reduce_store_qk(float* a, const float* bias,
                                                unsigned short* dst, int cs)
{
#pragma unroll
    for (int d = 0; d < 32; ++d) {
        a[d] += __shfl_xor(a[d], 16);
        a[d] += __shfl_xor(a[d], 32);
    }
    float v0, v1, v2, v3, v4, v5, v6, v7;
    if (cs == 0)      { v0=a[0];  v1=a[1];  v2=a[2];  v3=a[3];  v4=a[4];  v5=a[5];  v6=a[6];  v7=a[7]; }
    else if (cs == 1) { v0=a[8];  v1=a[9];  v2=a[10]; v3=a[11]; v4=a[12]; v5=a[13]; v6=a[14]; v7=a[15]; }
    else if (cs == 2) { v0=a[16]; v1=a[17]; v2=a[18]; v3=a[19]; v4=a[20]; v5=a[21]; v6=a[22]; v7=a[23]; }
    else              { v0=a[24]; v1=a[25]; v2=a[26]; v3=a[27]; v4=a[28]; v5=a[29]; v6=a[30]; v7=a[31]; }
    int d0 = cs * 8;
    v0 += bias[d0+0]; v1 += bias[d0+1]; v2 += bias[d0+2]; v3 += bias[d0+3];
    v4 += bias[d0+4]; v5 += bias[d0+5]; v6 += bias[d0+6]; v7 += bias[d0+7];
    int4 st;
    st.x = f2bf(v0) | ((unsigned)f2bf(v1) << 16);
    st.y = f2bf(v2) | ((unsigned)f2bf(v3) << 16);
    st.z = f2bf(v4) | ((unsigned)f2bf(v5) << 16);
    st.w = f2bf(v6) | ((unsigned)f2bf(v7) << 16);
    *(int4*)dst = st;
}

__global__ __launch_bounds__(256, 2) void proj_qk(
    const float* __restrict__ ef, const float* __restrict__ sf,
    const float* __restrict__ attn,
    const float* __restrict__ Qwt, const float* __restrict__ Kwt,
    const float* __restrict__ Qb, const float* __restrict__ Kb,
    unsigned short* __restrict__ qws, unsigned short* __restrict__ kws)
{
    int t  = threadIdx.x;
    int b  = blockIdx.x >> 6;
    int m0 = (blockIdx.x & 63) << 6;
    int cs   = (t >> 4) & 3;
    int mloc = (t & 15) + ((t >> 6) << 4);
    int mg   = m0 + mloc;

    float a[32];

    // ---- q : 512-channel input = concat(ef, sf); slice of 128 per cs ----
#pragma unroll
    for (int d = 0; d < 32; ++d) a[d] = 0.f;
    {
        const float* xbase = (cs < 2 ? ef : sf) +
                             ((size_t)(b * NC) + (size_t)(cs & 1) * 128) * NSP + mg;
        const float* wbase = Qwt + cs * 128 * 32;
        for (int i = 0; i < 128; ++i) {
            float xv = xbase[(size_t)i * NSP];
            const float4* wp = (const float4*)(wbase + i * 32);
            float4 w0 = wp[0], w1 = wp[1], w2 = wp[2], w3 = wp[3];
            float4 w4 = wp[4], w5 = wp[5], w6 = wp[6], w7 = wp[7];
            ACC4(w0, 0)  ACC4(w1, 4)  ACC4(w2, 8)  ACC4(w3, 12)
            ACC4(w4, 16) ACC4(w5, 20) ACC4(w6, 24) ACC4(w7, 28)
        }
    }
    reduce_store_qk(a, Qb, qws + ((size_t)(b * NSP + mg)) * 32 + cs * 8, cs);

    // ---- k : 256-channel input = Attn; slice of 64 per cs ----
#pragma unroll
    for (int d = 0; d < 32; ++d) a[d] = 0.f;
    {
        const float* xbase = attn + ((size_t)(b * NC) + (size_t)cs * 64) * NSP + mg;
        const float* wbase = Kwt + cs * 64 * 32;
        for (int i = 0; i < 64; ++i) {
            float xv = xbase[(size_t)i * NSP];
            const float4* wp = (const float4*)(wbase + i * 32);
            float4 w0 = wp[0], w1 = wp[1], w2 = wp[2], w3 = wp[3];
            float4 w4 = wp[4], w5 = wp[5], w6 = wp[6], w7 = wp[7];
            ACC4(w0, 0)  ACC4(w1, 4)  ACC4(w2, 8)  ACC4(w3, 12)
            ACC4(w4, 16) ACC4(w5, 20) ACC4(w6, 24) ACC4(w7, 28)
        }
    }
    reduce_store_qk(a, Kb, kws + ((size_t)(b * NSP + mg)) * 32 + cs * 8, cs);
}

// ---------------------------------------------------------------------------
// P2: v projection (bf16 MFMA GEMM). Out: vws tiled [B][128][256][32] bf16.
// Block: 64co x 64m tile; wave w owns m-slice [w*16, w*16+16).
// ---------------------------------------------------------------------------
__global__ __launch_bounds__(256, 2) void proj_v(
    const float* __restrict__ ef, const float* __restrict__ sf,
    const unsigned short* __restrict__ Vwbf, const float* __restrict__ Vb,
    unsigned short* __restrict__ vws)
{
    __shared__ unsigned short A_lds[64 * 40];   // [co][ci] padded
    __shared__ unsigned short B_lds[64 * 40];   // [m][ci]  padded (transposed x)

    int t = threadIdx.x;
    int mtile = blockIdx.x, cot = blockIdx.y, b = blockIdx.z;
    int m0 = mtile * 64;
    int w = t >> 6, lane = t & 63, quad = lane >> 4, l15 = lane & 15;

    f32x4 zero = {0.f, 0.f, 0.f, 0.f};
    f32x4 acc[4];
#pragma unroll
    for (int q = 0; q < 4; ++q) acc[q] = zero;

    int coS = t >> 2, segS = t & 3;     // A staging
    int ciS = t & 31, msegS = t >> 5;   // B staging (8 m's per thread)

    for (int ks = 0; ks < 16; ++ks) {
        int kc = ks * 32;
        *(int4*)&A_lds[coS * 40 + segS * 8] =
            *(const int4*)(Vwbf + (size_t)(cot * 64 + coS) * 512 + kc + segS * 8);
        {
            int cg = kc + ciS;
            const float* xp = (cg < 256 ? ef + ((size_t)(b * NC) + cg) * NSP
                                        : sf + ((size_t)(b * NC) + cg - 256) * NSP)
                              + m0 + msegS * 8;
            float4 x0 = *(const float4*)xp;
            float4 x1 = *(const float4*)(xp + 4);
            B_lds[(msegS * 8 + 0) * 40 + ciS] = f2bf(x0.x);
            B_lds[(msegS * 8 + 1) * 40 + ciS] = f2bf(x0.y);
            B_lds[(msegS * 8 + 2) * 40 + ciS] = f2bf(x0.z);
            B_lds[(msegS * 8 + 3) * 40 + ciS] = f2bf(x0.w);
            B_lds[(msegS * 8 + 4) * 40 + ciS] = f2bf(x1.x);
            B_lds[(msegS * 8 + 5) * 40 + ciS] = f2bf(x1.y);
            B_lds[(msegS * 8 + 6) * 40 + ciS] = f2bf(x1.z);
            B_lds[(msegS * 8 + 7) * 40 + ciS] = f2bf(x1.w);
        }
        __syncthreads();
        bf16x8 bfr = *(const bf16x8*)&B_lds[(w * 16 + l15) * 40 + quad * 8];
#pragma unroll
        for (int qc = 0; qc < 4; ++qc) {
            bf16x8 afr = *(const bf16x8*)&A_lds[(qc * 16 + l15) * 40 + quad * 8];
            acc[qc] = MFMA16(afr, bfr, acc[qc]);
        }
        __syncthreads();
    }

    int m = m0 + w * 16 + l15;
    int ntl = m >> 5, pos = m & 31;
    unsigned short* vp = vws + ((size_t)(b * 128 + ntl) * 256) * 32 + pos;
#pragma unroll
    for (int qc = 0; qc < 4; ++qc) {
        int cob = cot * 64 + qc * 16 + quad * 4;
        vp[(size_t)(cob + 0) * 32] = f2bf(acc[qc][0] + Vb[cob + 0]);
        vp[(size_t)(cob + 1) * 32] = f2bf(acc[qc][1] + Vb[cob + 1]);
        vp[(size_t)(cob + 2) * 32] = f2bf(acc[qc][2] + Vb[cob + 2]);
        vp[(size_t)(cob + 3) * 32] = f2bf(acc[qc][3] + Vb[cob + 3]);
    }
}

// ---------------------------------------------------------------------------
// ATT: fused scores/softmax(no-max)/PV/epilogue.
// 256 blocks = 4b x 64 m-chunks(64 queries). 4 waves: wave w computes S/P for
// queries [16w,16w+16) and accumulates out for ALL 64q x ch-slice [64w,64w+64).
// Single barrier per 32-key tile, double-buffered V/P in LDS.
// ---------------------------------------------------------------------------
__global__ __launch_bounds__(256, 1) void attention(
    const unsigned short* __restrict__ qws, const unsigned short* __restrict__ kws,
    const unsigned short* __restrict__ vws, const float* __restrict__ ef,
    const float* __restrict__ gamma, float* __restrict__ out)
{
    __shared__ unsigned short Vlds[2][256 * 40];  // [ch][key] padded
    __shared__ unsigned short Plds[2][64 * 40];   // [q][key]  padded
    __shared__ alignas(16) float denl[64];

    int t = threadIdx.x;
    int b  = blockIdx.x >> 6;
    int m0 = (blockIdx.x & 63) << 6;
    int w = t >> 6, lane = t & 63, quad = lane >> 4, l15 = lane & 15;

    // Q fragment: A[m=lane&15][k=quad*8+j], queries m0+16w+l15
    bf16x8 qf = *(const bf16x8*)(qws + ((size_t)(b * NSP + m0 + w * 16 + l15)) * 32 + quad * 8);

    f32x4 zero = {0.f, 0.f, 0.f, 0.f};
    f32x4 acc[4][4];
#pragma unroll
    for (int i = 0; i < 4; ++i)
#pragma unroll
        for (int j = 0; j < 4; ++j) acc[i][j] = zero;
    float lp0 = 0.f, lp1 = 0.f, lp2 = 0.f, lp3 = 0.f;

    // prefetch tile 0
    int4 vr0, vr1, vr2, vr3;
    {
        const int4* p = (const int4*)(vws + (size_t)(b * 128) * 8192);
        vr0 = p[t * 4 + 0]; vr1 = p[t * 4 + 1]; vr2 = p[t * 4 + 2]; vr3 = p[t * 4 + 3];
    }
    bf16x8 kf0 = *(const bf16x8*)(kws + ((size_t)(b * NSP + l15)) * 32 + quad * 8);
    bf16x8 kf1 = *(const bf16x8*)(kws + ((size_t)(b * NSP + 16 + l15)) * 32 + quad * 8);

    for (int nt = 0; nt < 128; ++nt) {
        int buf = nt & 1;
        // stage V tile (thread t owns channel row t)
        unsigned short* vd = &Vlds[buf][t * 40];
        *(int4*)(vd)      = vr0;
        *(int4*)(vd + 8)  = vr1;
        *(int4*)(vd + 16) = vr2;
        *(int4*)(vd + 24) = vr3;

        // scores for this wave's 16 queries vs 32 keys
        f32x4 s0 = MFMA16(qf, kf0, zero);
        f32x4 s1 = MFMA16(qf, kf1, zero);
        float e00 = __expf(s0[0]), e01 = __expf(s0[1]), e02 = __expf(s0[2]), e03 = __expf(s0[3]);
        float e10 = __expf(s1[0]), e11 = __expf(s1[1]), e12 = __expf(s1[2]), e13 = __expf(s1[3]);
        lp0 += e00 + e10; lp1 += e01 + e11; lp2 += e02 + e12; lp3 += e03 + e13;

        // P -> LDS (C-layout -> A-layout round trip). row = 16w+quad*4+r, col = l15 / l15+16
        unsigned short* pd = &Plds[buf][(w * 16 + quad * 4) * 40 + l15];
        pd[0]   = f2bf(e00); pd[16]  = f2bf(e10);
        pd[40]  = f2bf(e01); pd[56]  = f2bf(e11);
        pd[80]  = f2bf(e02); pd[96]  = f2bf(e12);
        pd[120] = f2bf(e03); pd[136] = f2bf(e13);

        // prefetch next tile (V regs + K fragments)
        int ntn = nt < 127 ? nt + 1 : 127;
        {
            const int4* p = (const int4*)(vws + (size_t)(b * 128 + ntn) * 8192);
            vr0 = p[t * 4 + 0]; vr1 = p[t * 4 + 1]; vr2 = p[t * 4 + 2]; vr3 = p[t * 4 + 3];
            int n0n = ntn * 32;
            kf0 = *(const bf16x8*)(kws + ((size_t)(b * NSP + n0n + l15)) * 32 + quad * 8);
            kf1 = *(const bf16x8*)(kws + ((size_t)(b * NSP + n0n + 16 + l15)) * 32 + quad * 8);
        }

        __syncthreads();

        // PV: 4 P-frags (all 64 q) x 4 V-frags (this wave's 64 ch) = 16 MFMAs
        bf16x8 pa0 = *(const bf16x8*)&Plds[buf][(0  + l15) * 40 + quad * 8];
        bf16x8 pa1 = *(const bf16x8*)&Plds[buf][(16 + l15) * 40 + quad * 8];
        bf16x8 pa2 = *(const bf16x8*)&Plds[buf][(32 + l15) * 40 + quad * 8];
        bf16x8 pa3 = *(const bf16x8*)&Plds[buf][(48 + l15) * 40 + quad * 8];
#pragma unroll
        for (int cc = 0; cc < 4; ++cc) {
            bf16x8 vb = *(const bf16x8*)&Vlds[buf][(w * 64 + cc * 16 + l15) * 40 + quad * 8];
            acc[0][cc] = MFMA16(pa0, vb, acc[0][cc]);
            acc[1][cc] = MFMA16(pa1, vb, acc[1][cc]);
            acc[2][cc] = MFMA16(pa2, vb, acc[2][cc]);
            acc[3][cc] = MFMA16(pa3, vb, acc[3][cc]);
        }
        // single barrier/iter is safe: next write to buf^1 happens after the
        // barrier of the iteration whose reads it could collide with.
    }

    // denominators: butterfly over the 16 key-column lanes
    lp0 += __shfl_xor(lp0, 1); lp0 += __shfl_xor(lp0, 2); lp0 += __shfl_xor(lp0, 4); lp0 += __shfl_xor(lp0, 8);
    lp1 += __shfl_xor(lp1, 1); lp1 += __shfl_xor(lp1, 2); lp1 += __shfl_xor(lp1, 4); lp1 += __shfl_xor(lp1, 8);
    lp2 += __shfl_xor(lp2, 1); lp2 += __shfl_xor(lp2, 2); lp2 += __shfl_xor(lp2, 4); lp2 += __shfl_xor(lp2, 8);
    lp3 += __shfl_xor(lp3, 1); lp3 += __shfl_xor(lp3, 2); lp3 += __shfl_xor(lp3, 4); lp3 += __shfl_xor(lp3, 8);
    if (l15 == 0) {
        int base = w * 16 + quad * 4;
        denl[base + 0] = lp0; denl[base + 1] = lp1;
        denl[base + 2] = lp2; denl[base + 3] = lp3;
    }
    __syncthreads();

    float g = gamma[0];
#pragma unroll
    for (int qc = 0; qc < 4; ++qc) {
        float4 dv = *(const float4*)&denl[qc * 16 + quad * 4];
        float r0 = g / dv.x, r1 = g / dv.y, r2 = g / dv.z, r3 = g / dv.w;
#pragma unroll
        for (int cc = 0; cc < 4; ++cc) {
            int ch = w * 64 + cc * 16 + l15;
            size_t off = ((size_t)(b * NC + ch)) * NSP + m0 + qc * 16 + quad * 4;
            float4 e = *(const float4*)(ef + off);
            float4 o;
            o.x = acc[qc][cc][0] * r0 + e.x;
            o.y = acc[qc][cc][1] * r1 + e.y;
            o.z = acc[qc][cc][2] * r2 + e.z;
            o.w = acc[qc][cc][3] * r3 + e.w;
            *(float4*)(out + off) = o;
        }
    }
}

// ---------------------------------------------------------------------------
extern "C" void kernel_launch(void* const* d_in, const int* in_sizes, int n_in,
                              void* d_out, int out_size, void* d_ws, size_t ws_size,
                              hipStream_t stream) {
    const float* ef    = (const float*)d_in[0];
    const float* sf    = (const float*)d_in[1];
    const float* attn  = (const float*)d_in[2];
    const float* Qw    = (const float*)d_in[3];
    const float* Qb    = (const float*)d_in[4];
    const float* Kw    = (const float*)d_in[5];
    const float* Kb    = (const float*)d_in[6];
    const float* Vw    = (const float*)d_in[7];
    const float* Vb    = (const float*)d_in[8];
    const float* gamma = (const float*)d_in[9];
    float* out = (float*)d_out;

    // workspace carve (≈10.4 MB total)
    unsigned short* qws = (unsigned short*)d_ws;        // [4][4096][32] bf16
    unsigned short* kws = qws + 4 * 4096 * 32;          // [4][4096][32] bf16
    unsigned short* vws = kws + 4 * 4096 * 32;          // [4][128][256][32] bf16
    float* Qwt = (float*)(vws + (size_t)4 * 128 * 256 * 32); // [512][32] f32
    float* Kwt = Qwt + 512 * 32;                         // [256][32] f32
    unsigned short* Vwbf = (unsigned short*)(Kwt + 256 * 32); // [256][512] bf16

    hipLaunchKernelGGL(prep_weights, dim3(64), dim3(256), 0, stream,
                       Qw, Kw, Vw, Qwt, Kwt, Vwbf);
    hipLaunchKernelGGL(proj_qk, dim3(256), dim3(256), 0, stream,
                       ef, sf, attn, Qwt, Kwt, Qb, Kb, qws, kws);
    hipLaunchKernelGGL(proj_v, dim3(64, 4, 4), dim3(256), 0, stream,
                       ef, sf, Vwbf, Vb, vws);
    hipLaunchKernelGGL(attention, dim3(256), dim3(256), 0, stream,
                       qws, kws, vws, ef, gamma, out);
}

// Round 2
// 202.413 us; speedup vs baseline: 1.4909x; 1.4909x over previous
//
#include <hip/hip_runtime.h>
#include <hip/hip_bf16.h>

typedef short bf16x8 __attribute__((ext_vector_type(8)));
typedef float f32x4 __attribute__((ext_vector_type(4)));

#define MFMA16(a, b, c) __builtin_amdgcn_mfma_f32_16x16x32_bf16(a, b, c, 0, 0, 0)

#define NB 4
#define NC 256
#define NSP 4096

// round-half-up bf16 (0.5 ulp, cheap: add + shift)
__device__ __forceinline__ unsigned short f2bf(float f) {
    return (unsigned short)((__float_as_uint(f) + 0x8000u) >> 16);
}
// packed pair: (bf(hi)<<16)|bf(lo) via v_perm_b32 — 3 VALU ops
__device__ __forceinline__ unsigned pk2bf(float hi, float lo) {
    return __builtin_amdgcn_perm(__float_as_uint(hi) + 0x8000u,
                                 __float_as_uint(lo) + 0x8000u, 0x07060302u);
}

// ---------------------------------------------------------------------------
// prep_w: weights -> bf16, natural [o][ci] layout (B-fragment friendly).
// ---------------------------------------------------------------------------
__global__ __launch_bounds__(256) void prep_w(
    const float* __restrict__ Qw, const float* __restrict__ Kw,
    const float* __restrict__ Vw,
    unsigned short* __restrict__ Qwbf, unsigned short* __restrict__ Kwbf,
    unsigned short* __restrict__ Vwbf)
{
    int i = blockIdx.x * 256 + threadIdx.x;   // 0..16383
    {   // Vw: 131072 elems, 8 per thread
        const float4* vs = (const float4*)(Vw + (size_t)i * 8);
        float4 a = vs[0], c = vs[1];
        int4 st;
        st.x = (int)pk2bf(a.y, a.x); st.y = (int)pk2bf(a.w, a.z);
        st.z = (int)pk2bf(c.y, c.x); st.w = (int)pk2bf(c.w, c.z);
        *(int4*)(Vwbf + (size_t)i * 8) = st;
    }
    if (i < 2048) {   // Qw: 16384 elems
        const float4* qs = (const float4*)(Qw + (size_t)i * 8);
        float4 a = qs[0], c = qs[1];
        int4 st;
        st.x = (int)pk2bf(a.y, a.x); st.y = (int)pk2bf(a.w, a.z);
        st.z = (int)pk2bf(c.y, c.x); st.w = (int)pk2bf(c.w, c.z);
        *(int4*)(Qwbf + (size_t)i * 8) = st;
    }
    if (i < 1024) {   // Kw: 8192 elems
        const float4* ks = (const float4*)(Kw + (size_t)i * 8);
        float4 a = ks[0], c = ks[1];
        int4 st;
        st.x = (int)pk2bf(a.y, a.x); st.y = (int)pk2bf(a.w, a.z);
        st.z = (int)pk2bf(c.y, c.x); st.w = (int)pk2bf(c.w, c.z);
        *(int4*)(Kwbf + (size_t)i * 8) = st;
    }
}

// ---------------------------------------------------------------------------
// prep_x: transpose + cvt. ef||sf -> xt[b][m][512] bf16; attn -> at[b][m][256].
// 64x64 tiles through LDS. Grid 3072 blocks x 256 thr.
// ---------------------------------------------------------------------------
__global__ __launch_bounds__(256) void prep_x(
    const float* __restrict__ ef, const float* __restrict__ sf,
    const float* __restrict__ attn,
    unsigned short* __restrict__ xt, unsigned short* __restrict__ at)
{
    __shared__ float tile[64][65];
    int gid = blockIdx.x;
    const float* src; unsigned short* dst;
    int mt, cdst0, CW;
    if (gid < 2048) {
        int b = gid >> 9, r = gid & 511;
        mt = r >> 3; int ct = r & 7;
        src = (ct < 4 ? ef : sf) + ((size_t)(b * NC) + (ct & 3) * 64) * NSP;
        dst = xt + (size_t)b * NSP * 512; cdst0 = ct * 64; CW = 512;
    } else {
        int g2 = gid - 2048;
        int b = g2 >> 8, r = g2 & 255;
        mt = r >> 2; int ct = r & 3;
        src = attn + ((size_t)(b * NC) + ct * 64) * NSP;
        dst = at + (size_t)b * NSP * 256; cdst0 = ct * 64; CW = 256;
    }
    int m0 = mt * 64;
    int t = threadIdx.x;
    int ml = t & 63, cl = t >> 6;
#pragma unroll
    for (int r = 0; r < 16; ++r)
        tile[ml][r * 4 + cl] = src[(size_t)(r * 4 + cl) * NSP + m0 + ml];
    __syncthreads();
    int cp = t & 31, mw = t >> 5;
#pragma unroll
    for (int r = 0; r < 8; ++r) {
        int m_l = r * 8 + mw;
        float v0 = tile[m_l][2 * cp], v1 = tile[m_l][2 * cp + 1];
        *(unsigned*)(dst + (size_t)(m0 + m_l) * CW + cdst0 + 2 * cp) = pk2bf(v1, v0);
    }
}

// ---------------------------------------------------------------------------
// proj_qk: LDS-free MFMA. q[m][32] k[m][32] bf16. Grid 256, block 256.
// Wave w owns m-tile m0+16w. A = xt/at rows (contig), B = Qwbf/Kwbf rows (contig).
// ---------------------------------------------------------------------------
__global__ __launch_bounds__(256) void proj_qk(
    const unsigned short* __restrict__ xt, const unsigned short* __restrict__ at,
    const unsigned short* __restrict__ Qwbf, const unsigned short* __restrict__ Kwbf,
    const float* __restrict__ Qb, const float* __restrict__ Kb,
    unsigned short* __restrict__ qws, unsigned short* __restrict__ kws)
{
    int t = threadIdx.x;
    int w = t >> 6, lane = t & 63, quad = lane >> 4, l15 = lane & 15;
    int b = blockIdx.x >> 6, m0 = (blockIdx.x & 63) * 64;
    int m = m0 + w * 16;

    f32x4 zero = {0.f, 0.f, 0.f, 0.f};
    f32x4 aq0 = zero, aq1 = zero, ak0 = zero, ak1 = zero;

    const unsigned short* xrow = xt + ((size_t)(b * NSP) + m + l15) * 512;
#pragma unroll
    for (int ks = 0; ks < 16; ++ks) {
        bf16x8 af = *(const bf16x8*)(xrow + ks * 32 + quad * 8);
        bf16x8 b0 = *(const bf16x8*)(Qwbf + (size_t)l15 * 512 + ks * 32 + quad * 8);
        bf16x8 b1 = *(const bf16x8*)(Qwbf + (size_t)(16 + l15) * 512 + ks * 32 + quad * 8);
        aq0 = MFMA16(af, b0, aq0);
        aq1 = MFMA16(af, b1, aq1);
    }
    const unsigned short* arow = at + ((size_t)(b * NSP) + m + l15) * 256;
#pragma unroll
    for (int ks = 0; ks < 8; ++ks) {
        bf16x8 af = *(const bf16x8*)(arow + ks * 32 + quad * 8);
        bf16x8 b0 = *(const bf16x8*)(Kwbf + (size_t)l15 * 256 + ks * 32 + quad * 8);
        bf16x8 b1 = *(const bf16x8*)(Kwbf + (size_t)(16 + l15) * 256 + ks * 32 + quad * 8);
        ak0 = MFMA16(af, b0, ak0);
        ak1 = MFMA16(af, b1, ak1);
    }
    float bq0 = Qb[l15], bq1 = Qb[16 + l15];
    float bk0 = Kb[l15], bk1 = Kb[16 + l15];
#pragma unroll
    for (int r = 0; r < 4; ++r) {
        size_t mr = (size_t)(b * NSP) + m + quad * 4 + r;
        qws[mr * 32 + l15]      = f2bf(aq0[r] + bq0);
        qws[mr * 32 + 16 + l15] = f2bf(aq1[r] + bq1);
        kws[mr * 32 + l15]      = f2bf(ak0[r] + bk0);
        kws[mr * 32 + 16 + l15] = f2bf(ak1[r] + bk1);
    }
}

// ---------------------------------------------------------------------------
// proj_v: LDS-free MFMA GEMM. vws[b][nt][ch][32] bf16, key dim PERMUTED:
// logical key k<16 -> slot 2k; k>=16 -> slot 2(k-16)+1 (matches attention's
// paired P packing — contraction order permuted identically on both operands).
// Grid (128 mtiles, 2 co-halves, 4 b), block 256 (wave = 32-co slice).
// ---------------------------------------------------------------------------
__global__ __launch_bounds__(256) void proj_v(
    const unsigned short* __restrict__ xt,
    const unsigned short* __restrict__ Vwbf, const float* __restrict__ Vb,
    unsigned short* __restrict__ vws)
{
    int t = threadIdx.x;
    int w = t >> 6, lane = t & 63, quad = lane >> 4, l15 = lane & 15;
    int mt = blockIdx.x, coh = blockIdx.y, b = blockIdx.z;
    int m0 = mt * 32;
    int co0 = coh * 128 + w * 32;

    f32x4 zero = {0.f, 0.f, 0.f, 0.f};
    f32x4 acc[2][2];
    acc[0][0] = zero; acc[0][1] = zero; acc[1][0] = zero; acc[1][1] = zero;

    const unsigned short* x0 = xt + ((size_t)(b * NSP) + m0 + l15) * 512;
    const unsigned short* x1 = x0 + 16 * 512;
    const unsigned short* vw0 = Vwbf + (size_t)(co0 + l15) * 512;
    const unsigned short* vw1 = Vwbf + (size_t)(co0 + 16 + l15) * 512;
#pragma unroll
    for (int ks = 0; ks < 16; ++ks) {
        bf16x8 a0 = *(const bf16x8*)(x0 + ks * 32 + quad * 8);
        bf16x8 a1 = *(const bf16x8*)(x1 + ks * 32 + quad * 8);
        bf16x8 b0 = *(const bf16x8*)(vw0 + ks * 32 + quad * 8);
        bf16x8 b1 = *(const bf16x8*)(vw1 + ks * 32 + quad * 8);
        acc[0][0] = MFMA16(a0, b0, acc[0][0]);
        acc[0][1] = MFMA16(a0, b1, acc[0][1]);
        acc[1][0] = MFMA16(a1, b0, acc[1][0]);
        acc[1][1] = MFMA16(a1, b1, acc[1][1]);
    }
#pragma unroll
    for (int mi = 0; mi < 2; ++mi)
#pragma unroll
        for (int ci = 0; ci < 2; ++ci) {
            int co = co0 + ci * 16 + l15;
            float bias = Vb[co];
            unsigned short* vp = vws + ((size_t)(b * 128 + mt) * 256 + co) * 32;
#pragma unroll
            for (int r = 0; r < 4; ++r)
                vp[2 * (quad * 4 + r) + mi] = f2bf(acc[mi][ci][r] + bias);
        }
}

// ---------------------------------------------------------------------------
// attention: 512 thr = 2 key-groups x 4 waves. No V LDS (direct global B-frags,
// disjoint ch slices). P through per-group dbuf LDS, packed-pair key layout.
// In-block merge of the two key-halves (softmax is max-free -> linear).
// ---------------------------------------------------------------------------
__global__ __launch_bounds__(512, 2) void attention(
    const unsigned short* __restrict__ qws, const unsigned short* __restrict__ kws,
    const unsigned short* __restrict__ vws, const float* __restrict__ ef,
    const float* __restrict__ gamma, float* __restrict__ out)
{
    __shared__ unsigned short Plds[2][2][64 * 40];
    __shared__ float mrg[256][68];
    __shared__ float denl[2][64];

    int t = threadIdx.x;
    int g = t >> 8, tl = t & 255;
    int w = tl >> 6, lane = tl & 63, quad = lane >> 4, l15 = lane & 15;
    int b = blockIdx.x >> 6, m0 = (blockIdx.x & 63) << 6;

    const unsigned short* kbase = kws + (size_t)(b * NSP) * 32;
    const unsigned short* vbase = vws + (size_t)(b * 128) * 8192;

    bf16x8 qf = *(const bf16x8*)(qws + ((size_t)(b * NSP) + m0 + w * 16 + l15) * 32 + quad * 8);

    f32x4 zero = {0.f, 0.f, 0.f, 0.f};
    f32x4 acc[4][4];
#pragma unroll
    for (int i = 0; i < 4; ++i)
#pragma unroll
        for (int j = 0; j < 4; ++j) acc[i][j] = zero;
    float lp0 = 0.f, lp1 = 0.f, lp2 = 0.f, lp3 = 0.f;

    int nt0 = g * 64;
    bf16x8 kf0 = *(const bf16x8*)(kbase + (size_t)(nt0 * 32 + l15) * 32 + quad * 8);
    bf16x8 kf1 = *(const bf16x8*)(kbase + (size_t)(nt0 * 32 + 16 + l15) * 32 + quad * 8);
    bf16x8 vf[4];
#pragma unroll
    for (int cc = 0; cc < 4; ++cc)
        vf[cc] = *(const bf16x8*)(vbase + (size_t)nt0 * 8192 + (w * 64 + cc * 16 + l15) * 32 + quad * 8);

    for (int it = 0; it < 64; ++it) {
        int buf = it & 1;
        f32x4 s0 = MFMA16(qf, kf0, zero);
        f32x4 s1 = MFMA16(qf, kf1, zero);
        float e00 = __expf(s0[0]), e01 = __expf(s0[1]), e02 = __expf(s0[2]), e03 = __expf(s0[3]);
        float e10 = __expf(s1[0]), e11 = __expf(s1[1]), e12 = __expf(s1[2]), e13 = __expf(s1[3]);
        lp0 += e00 + e10; lp1 += e01 + e11; lp2 += e02 + e12; lp3 += e03 + e13;

        // paired-key P store: u32 = (bf(e1?)<<16)|bf(e0?) at slot 2*l15
        {
            unsigned short* pb = &Plds[g][buf][(w * 16 + quad * 4) * 40 + 2 * l15];
            *(unsigned*)(pb)           = pk2bf(e10, e00);
            *(unsigned*)(pb + 40)      = pk2bf(e11, e01);
            *(unsigned*)(pb + 80)      = pk2bf(e12, e02);
            *(unsigned*)(pb + 120)     = pk2bf(e13, e03);
        }

        // prefetch next tile
        int itn = it + 1 < 64 ? it + 1 : 63;
        int ntn = nt0 + itn;
        kf0 = *(const bf16x8*)(kbase + (size_t)(ntn * 32 + l15) * 32 + quad * 8);
        kf1 = *(const bf16x8*)(kbase + (size_t)(ntn * 32 + 16 + l15) * 32 + quad * 8);
        bf16x8 vfn[4];
#pragma unroll
        for (int cc = 0; cc < 4; ++cc)
            vfn[cc] = *(const bf16x8*)(vbase + (size_t)ntn * 8192 + (w * 64 + cc * 16 + l15) * 32 + quad * 8);

        __syncthreads();

        bf16x8 pa0 = *(const bf16x8*)&Plds[g][buf][(0  + l15) * 40 + quad * 8];
        bf16x8 pa1 = *(const bf16x8*)&Plds[g][buf][(16 + l15) * 40 + quad * 8];
        bf16x8 pa2 = *(const bf16x8*)&Plds[g][buf][(32 + l15) * 40 + quad * 8];
        bf16x8 pa3 = *(const bf16x8*)&Plds[g][buf][(48 + l15) * 40 + quad * 8];
#pragma unroll
        for (int cc = 0; cc < 4; ++cc) {
            acc[0][cc] = MFMA16(pa0, vf[cc], acc[0][cc]);
            acc[1][cc] = MFMA16(pa1, vf[cc], acc[1][cc]);
            acc[2][cc] = MFMA16(pa2, vf[cc], acc[2][cc]);
            acc[3][cc] = MFMA16(pa3, vf[cc], acc[3][cc]);
        }
#pragma unroll
        for (int cc = 0; cc < 4; ++cc) vf[cc] = vfn[cc];
    }

    // denominator partials (per group)
    lp0 += __shfl_xor(lp0, 1); lp0 += __shfl_xor(lp0, 2); lp0 += __shfl_xor(lp0, 4); lp0 += __shfl_xor(lp0, 8);
    lp1 += __shfl_xor(lp1, 1); lp1 += __shfl_xor(lp1, 2); lp1 += __shfl_xor(lp1, 4); lp1 += __shfl_xor(lp1, 8);
    lp2 += __shfl_xor(lp2, 1); lp2 += __shfl_xor(lp2, 2); lp2 += __shfl_xor(lp2, 4); lp2 += __shfl_xor(lp2, 8);
    lp3 += __shfl_xor(lp3, 1); lp3 += __shfl_xor(lp3, 2); lp3 += __shfl_xor(lp3, 4); lp3 += __shfl_xor(lp3, 8);
    if (l15 == 0) {
        int base = w * 16 + quad * 4;
        denl[g][base + 0] = lp0; denl[g][base + 1] = lp1;
        denl[g][base + 2] = lp2; denl[g][base + 3] = lp3;
    }
    // group 1 exports its numerator partials ([ch][q+pad] so f32x4 is q-contig)
    if (g == 1) {
#pragma unroll
        for (int qc = 0; qc < 4; ++qc)
#pragma unroll
            for (int cc = 0; cc < 4; ++cc)
                *(f32x4*)&mrg[w * 64 + cc * 16 + l15][qc * 16 + quad * 4] = acc[qc][cc];
    }
    __syncthreads();

    if (g == 0) {
        float gam = gamma[0];
#pragma unroll
        for (int qc = 0; qc < 4; ++qc) {
            int qb = qc * 16 + quad * 4;
            float4 d0 = *(const float4*)&denl[0][qb];
            float4 d1 = *(const float4*)&denl[1][qb];
            float r0 = gam / (d0.x + d1.x), r1 = gam / (d0.y + d1.y);
            float r2 = gam / (d0.z + d1.z), r3 = gam / (d0.w + d1.w);
#pragma unroll
            for (int cc = 0; cc < 4; ++cc) {
                int ch = w * 64 + cc * 16 + l15;
                f32x4 part = *(const f32x4*)&mrg[ch][qb];
                size_t off = ((size_t)(b * NC + ch)) * NSP + m0 + qb;
                float4 e = *(const float4*)(ef + off);
                float4 o;
                o.x = (acc[qc][cc][0] + part[0]) * r0 + e.x;
                o.y = (acc[qc][cc][1] + part[1]) * r1 + e.y;
                o.z = (acc[qc][cc][2] + part[2]) * r2 + e.z;
                o.w = (acc[qc][cc][3] + part[3]) * r3 + e.w;
                *(float4*)(out + off) = o;
            }
        }
    }
}

// ---------------------------------------------------------------------------
extern "C" void kernel_launch(void* const* d_in, const int* in_sizes, int n_in,
                              void* d_out, int out_size, void* d_ws, size_t ws_size,
                              hipStream_t stream) {
    const float* ef    = (const float*)d_in[0];
    const float* sf    = (const float*)d_in[1];
    const float* attn  = (const float*)d_in[2];
    const float* Qw    = (const float*)d_in[3];
    const float* Qb    = (const float*)d_in[4];
    const float* Kw    = (const float*)d_in[5];
    const float* Kb    = (const float*)d_in[6];
    const float* Vw    = (const float*)d_in[7];
    const float* Vb    = (const float*)d_in[8];
    const float* gamma = (const float*)d_in[9];
    float* out = (float*)d_out;

    // workspace carve (~35.9 MB)
    unsigned short* qws  = (unsigned short*)d_ws;                    // 4*4096*32
    unsigned short* kws  = qws + (size_t)4 * 4096 * 32;              // 4*4096*32
    unsigned short* vws  = kws + (size_t)4 * 4096 * 32;              // 4*128*256*32
    unsigned short* xt   = vws + (size_t)4 * 128 * 256 * 32;         // 4*4096*512
    unsigned short* at   = xt  + (size_t)4 * 4096 * 512;             // 4*4096*256
    unsigned short* Qwbf = at  + (size_t)4 * 4096 * 256;             // 32*512
    unsigned short* Kwbf = Qwbf + 32 * 512;                          // 32*256
    unsigned short* Vwbf = Kwbf + 32 * 256;                          // 256*512

    hipLaunchKernelGGL(prep_w, dim3(64), dim3(256), 0, stream,
                       Qw, Kw, Vw, Qwbf, Kwbf, Vwbf);
    hipLaunchKernelGGL(prep_x, dim3(3072), dim3(256), 0, stream,
                       ef, sf, attn, xt, at);
    hipLaunchKernelGGL(proj_qk, dim3(256), dim3(256), 0, stream,
                       xt, at, Qwbf, Kwbf, Qb, Kb, qws, kws);
    hipLaunchKernelGGL(proj_v, dim3(128, 2, 4), dim3(256), 0, stream,
                       xt, Vwbf, Vb, vws);
    hipLaunchKernelGGL(attention, dim3(256), dim3(512), 0, stream,
                       qws, kws, vws, ef, gamma, out);
}

// Round 3
// 198.023 us; speedup vs baseline: 1.5240x; 1.0222x over previous
//
#include <hip/hip_runtime.h>
#include <hip/hip_bf16.h>

typedef short bf16x8 __attribute__((ext_vector_type(8)));
typedef float f32x4 __attribute__((ext_vector_type(4)));

#define MFMA16(a, b, c) __builtin_amdgcn_mfma_f32_16x16x32_bf16(a, b, c, 0, 0, 0)

#define NB 4
#define NC 256
#define NSP 4096
#define LOG2E 1.4426950408889634f

__device__ __forceinline__ unsigned short f2bf(float f) {
    return (unsigned short)((__float_as_uint(f) + 0x8000u) >> 16);
}
// packed pair: (bf(hi)<<16)|bf(lo) via v_perm_b32 — 3 VALU ops
__device__ __forceinline__ unsigned pk2bf(float hi, float lo) {
    return __builtin_amdgcn_perm(__float_as_uint(hi) + 0x8000u,
                                 __float_as_uint(lo) + 0x8000u, 0x07060302u);
}

// ---------------------------------------------------------------------------
// prep (fused): gid<3072: transpose+cvt x/attn -> xt[b][m][512], at[b][m][256];
//               gid>=3072: weights -> bf16 natural [o][ci] layout.
// ---------------------------------------------------------------------------
__global__ __launch_bounds__(256) void prep(
    const float* __restrict__ ef, const float* __restrict__ sf,
    const float* __restrict__ attn,
    const float* __restrict__ Qw, const float* __restrict__ Kw,
    const float* __restrict__ Vw,
    unsigned short* __restrict__ xt, unsigned short* __restrict__ at,
    unsigned short* __restrict__ Qwbf, unsigned short* __restrict__ Kwbf,
    unsigned short* __restrict__ Vwbf)
{
    __shared__ float tile[64][65];
    int gid = blockIdx.x;
    int t = threadIdx.x;

    if (gid >= 3072) {   // ---- weight prep ----
        int i = (gid - 3072) * 256 + t;   // 0..16383
        {
            const float4* vs = (const float4*)(Vw + (size_t)i * 8);
            float4 a = vs[0], c = vs[1];
            int4 st;
            st.x = (int)pk2bf(a.y, a.x); st.y = (int)pk2bf(a.w, a.z);
            st.z = (int)pk2bf(c.y, c.x); st.w = (int)pk2bf(c.w, c.z);
            *(int4*)(Vwbf + (size_t)i * 8) = st;
        }
        if (i < 2048) {
            const float4* qs = (const float4*)(Qw + (size_t)i * 8);
            float4 a = qs[0], c = qs[1];
            int4 st;
            st.x = (int)pk2bf(a.y, a.x); st.y = (int)pk2bf(a.w, a.z);
            st.z = (int)pk2bf(c.y, c.x); st.w = (int)pk2bf(c.w, c.z);
            *(int4*)(Qwbf + (size_t)i * 8) = st;
        }
        if (i < 1024) {
            const float4* ks = (const float4*)(Kw + (size_t)i * 8);
            float4 a = ks[0], c = ks[1];
            int4 st;
            st.x = (int)pk2bf(a.y, a.x); st.y = (int)pk2bf(a.w, a.z);
            st.z = (int)pk2bf(c.y, c.x); st.w = (int)pk2bf(c.w, c.z);
            *(int4*)(Kwbf + (size_t)i * 8) = st;
        }
        return;
    }

    // ---- transpose prep ----
    const float* src; unsigned short* dst;
    int mt, cdst0, CW;
    if (gid < 2048) {
        int b = gid >> 9, r = gid & 511;
        mt = r >> 3; int ct = r & 7;
        src = (ct < 4 ? ef : sf) + ((size_t)(b * NC) + (ct & 3) * 64) * NSP;
        dst = xt + (size_t)b * NSP * 512; cdst0 = ct * 64; CW = 512;
    } else {
        int g2 = gid - 2048;
        int b = g2 >> 8, r = g2 & 255;
        mt = r >> 2; int ct = r & 3;
        src = attn + ((size_t)(b * NC) + ct * 64) * NSP;
        dst = at + (size_t)b * NSP * 256; cdst0 = ct * 64; CW = 256;
    }
    int m0 = mt * 64;
    int ml = t & 63, cl = t >> 6;
#pragma unroll
    for (int r = 0; r < 16; ++r)
        tile[ml][r * 4 + cl] = src[(size_t)(r * 4 + cl) * NSP + m0 + ml];
    __syncthreads();
    int cp = t & 31, mw = t >> 5;
#pragma unroll
    for (int r = 0; r < 8; ++r) {
        int m_l = r * 8 + mw;
        float v0 = tile[m_l][2 * cp], v1 = tile[m_l][2 * cp + 1];
        *(unsigned*)(dst + (size_t)(m0 + m_l) * CW + cdst0 + 2 * cp) = pk2bf(v1, v0);
    }
}

// ---------------------------------------------------------------------------
// proj (fused): bi<256 q-proj (LOG2E folded) | bi<512 k-proj | else v-proj.
// All LDS-free MFMA with contiguous global A/B fragment loads.
// ---------------------------------------------------------------------------
__global__ __launch_bounds__(256, 4) void proj(
    const unsigned short* __restrict__ xt, const unsigned short* __restrict__ at,
    const unsigned short* __restrict__ Qwbf, const unsigned short* __restrict__ Kwbf,
    const unsigned short* __restrict__ Vwbf,
    const float* __restrict__ Qb, const float* __restrict__ Kb,
    const float* __restrict__ Vb,
    unsigned short* __restrict__ qws, unsigned short* __restrict__ kws,
    unsigned short* __restrict__ vws)
{
    int bi = blockIdx.x;
    int t = threadIdx.x;
    int w = t >> 6, lane = t & 63, quad = lane >> 4, l15 = lane & 15;
    f32x4 zero = {0.f, 0.f, 0.f, 0.f};

    if (bi < 256) {            // ---------- q projection ----------
        int b = bi >> 6, m = (bi & 63) * 64 + w * 16;
        f32x4 a0 = zero, a1 = zero;
        const unsigned short* xrow = xt + ((size_t)(b * NSP) + m + l15) * 512;
#pragma unroll 4
        for (int ks = 0; ks < 16; ++ks) {
            bf16x8 af = *(const bf16x8*)(xrow + ks * 32 + quad * 8);
            bf16x8 b0 = *(const bf16x8*)(Qwbf + (size_t)l15 * 512 + ks * 32 + quad * 8);
            bf16x8 b1 = *(const bf16x8*)(Qwbf + (size_t)(16 + l15) * 512 + ks * 32 + quad * 8);
            a0 = MFMA16(af, b0, a0);
            a1 = MFMA16(af, b1, a1);
        }
        float bq0 = Qb[l15], bq1 = Qb[16 + l15];
#pragma unroll
        for (int r = 0; r < 4; ++r) {
            size_t mr = (size_t)(b * NSP) + m + quad * 4 + r;
            qws[mr * 32 + l15]      = f2bf((a0[r] + bq0) * LOG2E);
            qws[mr * 32 + 16 + l15] = f2bf((a1[r] + bq1) * LOG2E);
        }
    } else if (bi < 512) {     // ---------- k projection ----------
        int r2 = bi - 256;
        int b = r2 >> 6, m = (r2 & 63) * 64 + w * 16;
        f32x4 a0 = zero, a1 = zero;
        const unsigned short* arow = at + ((size_t)(b * NSP) + m + l15) * 256;
#pragma unroll 4
        for (int ks = 0; ks < 8; ++ks) {
            bf16x8 af = *(const bf16x8*)(arow + ks * 32 + quad * 8);
            bf16x8 b0 = *(const bf16x8*)(Kwbf + (size_t)l15 * 256 + ks * 32 + quad * 8);
            bf16x8 b1 = *(const bf16x8*)(Kwbf + (size_t)(16 + l15) * 256 + ks * 32 + quad * 8);
            a0 = MFMA16(af, b0, a0);
            a1 = MFMA16(af, b1, a1);
        }
        float bk0 = Kb[l15], bk1 = Kb[16 + l15];
#pragma unroll
        for (int r = 0; r < 4; ++r) {
            size_t mr = (size_t)(b * NSP) + m + quad * 4 + r;
            kws[mr * 32 + l15]      = f2bf(a0[r] + bk0);
            kws[mr * 32 + 16 + l15] = f2bf(a1[r] + bk1);
        }
    } else {                   // ---------- v projection ----------
        int r2 = bi - 512;
        int mt = r2 & 127, coh = (r2 >> 7) & 1, b = r2 >> 8;
        int m0 = mt * 32;
        int co0 = coh * 128 + w * 32;

        f32x4 acc[2][2];
        acc[0][0] = zero; acc[0][1] = zero; acc[1][0] = zero; acc[1][1] = zero;

        const unsigned short* x0 = xt + ((size_t)(b * NSP) + m0 + l15) * 512;
        const unsigned short* x1 = x0 + 16 * 512;
        const unsigned short* vw0 = Vwbf + (size_t)(co0 + l15) * 512;
        const unsigned short* vw1 = Vwbf + (size_t)(co0 + 16 + l15) * 512;
#pragma unroll 4
        for (int ks = 0; ks < 16; ++ks) {
            bf16x8 a0 = *(const bf16x8*)(x0 + ks * 32 + quad * 8);
            bf16x8 a1 = *(const bf16x8*)(x1 + ks * 32 + quad * 8);
            bf16x8 b0 = *(const bf16x8*)(vw0 + ks * 32 + quad * 8);
            bf16x8 b1 = *(const bf16x8*)(vw1 + ks * 32 + quad * 8);
            acc[0][0] = MFMA16(a0, b0, acc[0][0]);
            acc[0][1] = MFMA16(a0, b1, acc[0][1]);
            acc[1][0] = MFMA16(a1, b0, acc[1][0]);
            acc[1][1] = MFMA16(a1, b1, acc[1][1]);
        }
#pragma unroll
        for (int mi = 0; mi < 2; ++mi)
#pragma unroll
            for (int ci = 0; ci < 2; ++ci) {
                int co = co0 + ci * 16 + l15;
                float bias = Vb[co];
                unsigned short* vp = vws + ((size_t)(b * 128 + mt) * 256 + co) * 32;
#pragma unroll
                for (int r = 0; r < 4; ++r)
                    vp[2 * (quad * 4 + r) + mi] = f2bf(acc[mi][ci][r] + bias);
            }
    }
}

// ---------------------------------------------------------------------------
// attention: 512 thr = 2 key-groups x 4 waves, 64 queries/block, 64 keys/iter
// (32 barriers). q pre-scaled by log2e -> raw v_exp_f32. Direct global V
// fragments (disjoint ch slices). Key-paired P packing matches vws layout.
// ---------------------------------------------------------------------------
__global__ __launch_bounds__(512, 2) void attention(
    const unsigned short* __restrict__ qws, const unsigned short* __restrict__ kws,
    const unsigned short* __restrict__ vws, const float* __restrict__ ef,
    const float* __restrict__ gamma, float* __restrict__ out)
{
    __shared__ unsigned short Plds[2][2][64 * 72];   // [g][buf][q][72]
    __shared__ float mrg[256][68];
    __shared__ float denl[2][64];

    int t = threadIdx.x;
    int g = t >> 8, tl = t & 255;
    int w = tl >> 6, lane = tl & 63, quad = lane >> 4, l15 = lane & 15;
    int b = blockIdx.x >> 6, m0 = (blockIdx.x & 63) << 6;

    const unsigned short* kbase = kws + (size_t)(b * NSP) * 32;
    const unsigned short* vbase = vws + (size_t)(b * 128) * 8192;

    bf16x8 qf = *(const bf16x8*)(qws + ((size_t)(b * NSP) + m0 + w * 16 + l15) * 32 + quad * 8);

    f32x4 zero = {0.f, 0.f, 0.f, 0.f};
    f32x4 acc[4][4];
#pragma unroll
    for (int i = 0; i < 4; ++i)
#pragma unroll
        for (int j = 0; j < 4; ++j) acc[i][j] = zero;
    float lp0 = 0.f, lp1 = 0.f, lp2 = 0.f, lp3 = 0.f;

    int tt0 = g * 64;   // first 32-key tile of this group
    bf16x8 kf[4];
#pragma unroll
    for (int j = 0; j < 4; ++j)
        kf[j] = *(const bf16x8*)(kbase + (size_t)((tt0 + (j >> 1)) * 32 + (j & 1) * 16 + l15) * 32 + quad * 8);
    bf16x8 vf[2][4];
#pragma unroll
    for (int h = 0; h < 2; ++h)
#pragma unroll
        for (int cc = 0; cc < 4; ++cc)
            vf[h][cc] = *(const bf16x8*)(vbase + (size_t)(tt0 + h) * 8192 + (w * 64 + cc * 16 + l15) * 32 + quad * 8);

    for (int it = 0; it < 32; ++it) {
        int buf = it & 1;
        f32x4 s0 = MFMA16(qf, kf[0], zero);
        f32x4 s1 = MFMA16(qf, kf[1], zero);
        f32x4 s2 = MFMA16(qf, kf[2], zero);
        f32x4 s3 = MFMA16(qf, kf[3], zero);

        float e0[4], e1[4], e2[4], e3[4];
#pragma unroll
        for (int r = 0; r < 4; ++r) {
            e0[r] = __builtin_amdgcn_exp2f(s0[r]);
            e1[r] = __builtin_amdgcn_exp2f(s1[r]);
            e2[r] = __builtin_amdgcn_exp2f(s2[r]);
            e3[r] = __builtin_amdgcn_exp2f(s3[r]);
        }
        lp0 += (e0[0] + e1[0]) + (e2[0] + e3[0]);
        lp1 += (e0[1] + e1[1]) + (e2[1] + e3[1]);
        lp2 += (e0[2] + e1[2]) + (e2[2] + e3[2]);
        lp3 += (e0[3] + e1[3]) + (e2[3] + e3[3]);

        // P rows q=w*16+quad*4+r; u32 slot l15 = keys (l15,l15+16) of tile h
        unsigned short* pd = &Plds[g][buf][(w * 16 + quad * 4) * 72 + 2 * l15];
#pragma unroll
        for (int r = 0; r < 4; ++r) {
            *(unsigned*)(pd + r * 72)      = pk2bf(e1[r], e0[r]);
            *(unsigned*)(pd + r * 72 + 32) = pk2bf(e3[r], e2[r]);
        }

        // prefetch next iteration
        int itn = it + 1 < 32 ? it + 1 : 31;
        int ttn = tt0 + 2 * itn;
#pragma unroll
        for (int j = 0; j < 4; ++j)
            kf[j] = *(const bf16x8*)(kbase + (size_t)((ttn + (j >> 1)) * 32 + (j & 1) * 16 + l15) * 32 + quad * 8);
        bf16x8 vfn[2][4];
#pragma unroll
        for (int h = 0; h < 2; ++h)
#pragma unroll
            for (int cc = 0; cc < 4; ++cc)
                vfn[h][cc] = *(const bf16x8*)(vbase + (size_t)(ttn + h) * 8192 + (w * 64 + cc * 16 + l15) * 32 + quad * 8);

        __syncthreads();

#pragma unroll
        for (int h = 0; h < 2; ++h) {
            bf16x8 pa0 = *(const bf16x8*)&Plds[g][buf][(0  + l15) * 72 + h * 32 + quad * 8];
            bf16x8 pa1 = *(const bf16x8*)&Plds[g][buf][(16 + l15) * 72 + h * 32 + quad * 8];
            bf16x8 pa2 = *(const bf16x8*)&Plds[g][buf][(32 + l15) * 72 + h * 32 + quad * 8];
            bf16x8 pa3 = *(const bf16x8*)&Plds[g][buf][(48 + l15) * 72 + h * 32 + quad * 8];
#pragma unroll
            for (int cc = 0; cc < 4; ++cc) {
                acc[0][cc] = MFMA16(pa0, vf[h][cc], acc[0][cc]);
                acc[1][cc] = MFMA16(pa1, vf[h][cc], acc[1][cc]);
                acc[2][cc] = MFMA16(pa2, vf[h][cc], acc[2][cc]);
                acc[3][cc] = MFMA16(pa3, vf[h][cc], acc[3][cc]);
            }
        }
#pragma unroll
        for (int h = 0; h < 2; ++h)
#pragma unroll
            for (int cc = 0; cc < 4; ++cc) vf[h][cc] = vfn[h][cc];
    }

    // per-group denominator partials
    lp0 += __shfl_xor(lp0, 1); lp0 += __shfl_xor(lp0, 2); lp0 += __shfl_xor(lp0, 4); lp0 += __shfl_xor(lp0, 8);
    lp1 += __shfl_xor(lp1, 1); lp1 += __shfl_xor(lp1, 2); lp1 += __shfl_xor(lp1, 4); lp1 += __shfl_xor(lp1, 8);
    lp2 += __shfl_xor(lp2, 1); lp2 += __shfl_xor(lp2, 2); lp2 += __shfl_xor(lp2, 4); lp2 += __shfl_xor(lp2, 8);
    lp3 += __shfl_xor(lp3, 1); lp3 += __shfl_xor(lp3, 2); lp3 += __shfl_xor(lp3, 4); lp3 += __shfl_xor(lp3, 8);
    if (l15 == 0) {
        int base = w * 16 + quad * 4;
        denl[g][base + 0] = lp0; denl[g][base + 1] = lp1;
        denl[g][base + 2] = lp2; denl[g][base + 3] = lp3;
    }
    if (g == 1) {
#pragma unroll
        for (int qc = 0; qc < 4; ++qc)
#pragma unroll
            for (int cc = 0; cc < 4; ++cc)
                *(f32x4*)&mrg[w * 64 + cc * 16 + l15][qc * 16 + quad * 4] = acc[qc][cc];
    }
    __syncthreads();

    if (g == 0) {
        float gam = gamma[0];
#pragma unroll
        for (int qc = 0; qc < 4; ++qc) {
            int qb = qc * 16 + quad * 4;
            float4 d0 = *(const float4*)&denl[0][qb];
            float4 d1 = *(const float4*)&denl[1][qb];
            float r0 = gam / (d0.x + d1.x), r1 = gam / (d0.y + d1.y);
            float r2 = gam / (d0.z + d1.z), r3 = gam / (d0.w + d1.w);
#pragma unroll
            for (int cc = 0; cc < 4; ++cc) {
                int ch = w * 64 + cc * 16 + l15;
                f32x4 part = *(const f32x4*)&mrg[ch][qb];
                size_t off = ((size_t)(b * NC + ch)) * NSP + m0 + qb;
                float4 e = *(const float4*)(ef + off);
                float4 o;
                o.x = (acc[qc][cc][0] + part[0]) * r0 + e.x;
                o.y = (acc[qc][cc][1] + part[1]) * r1 + e.y;
                o.z = (acc[qc][cc][2] + part[2]) * r2 + e.z;
                o.w = (acc[qc][cc][3] + part[3]) * r3 + e.w;
                *(float4*)(out + off) = o;
            }
        }
    }
}

// ---------------------------------------------------------------------------
extern "C" void kernel_launch(void* const* d_in, const int* in_sizes, int n_in,
                              void* d_out, int out_size, void* d_ws, size_t ws_size,
                              hipStream_t stream) {
    const float* ef    = (const float*)d_in[0];
    const float* sf    = (const float*)d_in[1];
    const float* attn  = (const float*)d_in[2];
    const float* Qw    = (const float*)d_in[3];
    const float* Qb    = (const float*)d_in[4];
    const float* Kw    = (const float*)d_in[5];
    const float* Kb    = (const float*)d_in[6];
    const float* Vw    = (const float*)d_in[7];
    const float* Vb    = (const float*)d_in[8];
    const float* gamma = (const float*)d_in[9];
    float* out = (float*)d_out;

    unsigned short* qws  = (unsigned short*)d_ws;                    // 4*4096*32
    unsigned short* kws  = qws + (size_t)4 * 4096 * 32;              // 4*4096*32
    unsigned short* vws  = kws + (size_t)4 * 4096 * 32;              // 4*128*256*32
    unsigned short* xt   = vws + (size_t)4 * 128 * 256 * 32;         // 4*4096*512
    unsigned short* at   = xt  + (size_t)4 * 4096 * 512;             // 4*4096*256
    unsigned short* Qwbf = at  + (size_t)4 * 4096 * 256;             // 32*512
    unsigned short* Kwbf = Qwbf + 32 * 512;                          // 32*256
    unsigned short* Vwbf = Kwbf + 32 * 256;                          // 256*512

    hipLaunchKernelGGL(prep, dim3(3136), dim3(256), 0, stream,
                       ef, sf, attn, Qw, Kw, Vw, xt, at, Qwbf, Kwbf, Vwbf);
    hipLaunchKernelGGL(proj, dim3(1536), dim3(256), 0, stream,
                       xt, at, Qwbf, Kwbf, Vwbf, Qb, Kb, Vb, qws, kws, vws);
    hipLaunchKernelGGL(attention, dim3(256), dim3(512), 0, stream,
                       qws, kws, vws, ef, gamma, out);
}

// Round 8
// 193.812 us; speedup vs baseline: 1.5571x; 1.0217x over previous
//
#include <hip/hip_runtime.h>
#include <hip/hip_bf16.h>

typedef short bf16x8 __attribute__((ext_vector_type(8)));
typedef float f32x4 __attribute__((ext_vector_type(4)));

#define MFMA16(a, b, c) __builtin_amdgcn_mfma_f32_16x16x32_bf16(a, b, c, 0, 0, 0)

#define NB 4
#define NC 256
#define NSP 4096
#define LOG2E 1.4426950408889634f

__device__ __forceinline__ unsigned short f2bf(float f) {
    return (unsigned short)((__float_as_uint(f) + 0x8000u) >> 16);
}
// packed pair: (bf(hi)<<16)|bf(lo) via v_perm_b32 — 3 VALU ops
__device__ __forceinline__ unsigned pk2bf(float hi, float lo) {
    return __builtin_amdgcn_perm(__float_as_uint(hi) + 0x8000u,
                                 __float_as_uint(lo) + 0x8000u, 0x07060302u);
}

// ---------------------------------------------------------------------------
// prep_w: weights -> bf16, natural [o][ci] layout. (R2-proven verbatim)
// ---------------------------------------------------------------------------
__global__ __launch_bounds__(256) void prep_w(
    const float* __restrict__ Qw, const float* __restrict__ Kw,
    const float* __restrict__ Vw,
    unsigned short* __restrict__ Qwbf, unsigned short* __restrict__ Kwbf,
    unsigned short* __restrict__ Vwbf)
{
    int i = blockIdx.x * 256 + threadIdx.x;   // 0..16383
    {
        const float4* vs = (const float4*)(Vw + (size_t)i * 8);
        float4 a = vs[0], c = vs[1];
        int4 st;
        st.x = (int)pk2bf(a.y, a.x); st.y = (int)pk2bf(a.w, a.z);
        st.z = (int)pk2bf(c.y, c.x); st.w = (int)pk2bf(c.w, c.z);
        *(int4*)(Vwbf + (size_t)i * 8) = st;
    }
    if (i < 2048) {
        const float4* qs = (const float4*)(Qw + (size_t)i * 8);
        float4 a = qs[0], c = qs[1];
        int4 st;
        st.x = (int)pk2bf(a.y, a.x); st.y = (int)pk2bf(a.w, a.z);
        st.z = (int)pk2bf(c.y, c.x); st.w = (int)pk2bf(c.w, c.z);
        *(int4*)(Qwbf + (size_t)i * 8) = st;
    }
    if (i < 1024) {
        const float4* ks = (const float4*)(Kw + (size_t)i * 8);
        float4 a = ks[0], c = ks[1];
        int4 st;
        st.x = (int)pk2bf(a.y, a.x); st.y = (int)pk2bf(a.w, a.z);
        st.z = (int)pk2bf(c.y, c.x); st.w = (int)pk2bf(c.w, c.z);
        *(int4*)(Kwbf + (size_t)i * 8) = st;
    }
}

// ---------------------------------------------------------------------------
// proj_q: WAVE-UNIFORM. Grid (128 mt, 4 b), 256 thr. Per 64-ci chunk of
// concat(ef,sf): stage x[32m][64ci] fp32->bf16 into LDS (single buffer,
// stage/sync/mfma/sync — R1-proven shape), then each wave does its (mi,oh)
// slice: 2 MFMAs. Output qws[b][m][32] bf16 with LOG2E folded.
// ---------------------------------------------------------------------------
__global__ __launch_bounds__(256) void proj_q(
    const float* __restrict__ ef, const float* __restrict__ sf,
    const unsigned short* __restrict__ Qwbf, const float* __restrict__ Qb,
    unsigned short* __restrict__ qws)
{
    __shared__ __align__(16) unsigned short xt[32][72];

    int t = threadIdx.x;
    int w = t >> 6, lane = t & 63, quad = lane >> 4, l15 = lane & 15;
    int mt = blockIdx.x, b = blockIdx.y, m0 = mt * 32;
    int ci = t & 63, sm = t >> 6;       // sm == w
    int mi = w >> 1, oh = w & 1;        // per-wave DATA slice (uniform code)

    f32x4 acc = {0.f, 0.f, 0.f, 0.f};

    for (int c = 0; c < 8; ++c) {
        const float* src = (c < 4 ? ef : sf) +
                           ((size_t)(b * NC) + (c & 3) * 64 + ci) * NSP + m0 + sm * 8;
        float4 x0 = *(const float4*)src;
        float4 x1 = *(const float4*)(src + 4);
        __syncthreads();   // protect previous chunk's LDS reads
        unsigned short* xd = &xt[sm * 8][ci];
        xd[0]   = f2bf(x0.x); xd[72]  = f2bf(x0.y);
        xd[144] = f2bf(x0.z); xd[216] = f2bf(x0.w);
        xd[288] = f2bf(x1.x); xd[360] = f2bf(x1.y);
        xd[432] = f2bf(x1.z); xd[504] = f2bf(x1.w);
        __syncthreads();
        int ci0 = c * 64;
#pragma unroll
        for (int ks = 0; ks < 2; ++ks) {
            bf16x8 a  = *(const bf16x8*)&xt[mi * 16 + l15][ks * 32 + quad * 8];
            bf16x8 bq = *(const bf16x8*)(Qwbf + (size_t)(oh * 16 + l15) * 512 + ci0 + ks * 32 + quad * 8);
            acc = MFMA16(a, bq, acc);
        }
    }

    int o = oh * 16 + l15;
    float bb = Qb[o];
#pragma unroll
    for (int r = 0; r < 4; ++r) {
        int m = m0 + mi * 16 + quad * 4 + r;
        qws[((size_t)(b * NSP) + m) * 32 + o] = f2bf((acc[r] + bb) * LOG2E);
    }
}

// ---------------------------------------------------------------------------
// proj_k: same shape as proj_q over attn (4 chunks, Kwbf 256-wide), no LOG2E.
// ---------------------------------------------------------------------------
__global__ __launch_bounds__(256) void proj_k(
    const float* __restrict__ attn,
    const unsigned short* __restrict__ Kwbf, const float* __restrict__ Kb,
    unsigned short* __restrict__ kws)
{
    __shared__ __align__(16) unsigned short xt[32][72];

    int t = threadIdx.x;
    int w = t >> 6, lane = t & 63, quad = lane >> 4, l15 = lane & 15;
    int mt = blockIdx.x, b = blockIdx.y, m0 = mt * 32;
    int ci = t & 63, sm = t >> 6;
    int mi = w >> 1, oh = w & 1;

    f32x4 acc = {0.f, 0.f, 0.f, 0.f};

    for (int c = 0; c < 4; ++c) {
        const float* src = attn + ((size_t)(b * NC) + c * 64 + ci) * NSP + m0 + sm * 8;
        float4 x0 = *(const float4*)src;
        float4 x1 = *(const float4*)(src + 4);
        __syncthreads();
        unsigned short* xd = &xt[sm * 8][ci];
        xd[0]   = f2bf(x0.x); xd[72]  = f2bf(x0.y);
        xd[144] = f2bf(x0.z); xd[216] = f2bf(x0.w);
        xd[288] = f2bf(x1.x); xd[360] = f2bf(x1.y);
        xd[432] = f2bf(x1.z); xd[504] = f2bf(x1.w);
        __syncthreads();
        int ci0 = c * 64;
#pragma unroll
        for (int ks = 0; ks < 2; ++ks) {
            bf16x8 a  = *(const bf16x8*)&xt[mi * 16 + l15][ks * 32 + quad * 8];
            bf16x8 bk = *(const bf16x8*)(Kwbf + (size_t)(oh * 16 + l15) * 256 + ci0 + ks * 32 + quad * 8);
            acc = MFMA16(a, bk, acc);
        }
    }

    int o = oh * 16 + l15;
    float bb = Kb[o];
#pragma unroll
    for (int r = 0; r < 4; ++r) {
        int m = m0 + mi * 16 + quad * 4 + r;
        kws[((size_t)(b * NSP) + m) * 32 + o] = f2bf(acc[r] + bb);
    }
}

// ---------------------------------------------------------------------------
// proj_v: WAVE-UNIFORM. Grid (128 mt, 4 b), 256 thr. Wave w owns co-slice
// w*64..w*64+63 (4 frags) x all 32 m (2 frags) -> acc[2][4], 16 MFMAs/chunk.
// Output vws[b][mt][256][32] bf16, paired-key slots (u32 j: keys j / 16+j).
// ---------------------------------------------------------------------------
__global__ __launch_bounds__(256) void proj_v(
    const float* __restrict__ ef, const float* __restrict__ sf,
    const unsigned short* __restrict__ Vwbf, const float* __restrict__ Vb,
    unsigned short* __restrict__ vws)
{
    __shared__ __align__(16) unsigned short xt[32][72];

    int t = threadIdx.x;
    int w = t >> 6, lane = t & 63, quad = lane >> 4, l15 = lane & 15;
    int mt = blockIdx.x, b = blockIdx.y, m0 = mt * 32;
    int ci = t & 63, sm = t >> 6;

    f32x4 zero = {0.f, 0.f, 0.f, 0.f};
    f32x4 acc[2][4];
#pragma unroll
    for (int mi = 0; mi < 2; ++mi)
#pragma unroll
        for (int ot = 0; ot < 4; ++ot) acc[mi][ot] = zero;

    for (int c = 0; c < 8; ++c) {
        const float* src = (c < 4 ? ef : sf) +
                           ((size_t)(b * NC) + (c & 3) * 64 + ci) * NSP + m0 + sm * 8;
        float4 x0 = *(const float4*)src;
        float4 x1 = *(const float4*)(src + 4);
        __syncthreads();
        unsigned short* xd = &xt[sm * 8][ci];
        xd[0]   = f2bf(x0.x); xd[72]  = f2bf(x0.y);
        xd[144] = f2bf(x0.z); xd[216] = f2bf(x0.w);
        xd[288] = f2bf(x1.x); xd[360] = f2bf(x1.y);
        xd[432] = f2bf(x1.z); xd[504] = f2bf(x1.w);
        __syncthreads();
        int ci0 = c * 64;
#pragma unroll
        for (int ks = 0; ks < 2; ++ks) {
            bf16x8 a0 = *(const bf16x8*)&xt[l15][ks * 32 + quad * 8];
            bf16x8 a1 = *(const bf16x8*)&xt[16 + l15][ks * 32 + quad * 8];
#pragma unroll
            for (int ot = 0; ot < 4; ++ot) {
                bf16x8 bv = *(const bf16x8*)(Vwbf + (size_t)(w * 64 + ot * 16 + l15) * 512 + ci0 + ks * 32 + quad * 8);
                acc[0][ot] = MFMA16(a0, bv, acc[0][ot]);
                acc[1][ot] = MFMA16(a1, bv, acc[1][ot]);
            }
        }
    }

#pragma unroll
    for (int ot = 0; ot < 4; ++ot) {
        int ch = w * 64 + ot * 16 + l15;
        float bias = Vb[ch];
        unsigned* vp = (unsigned*)(vws + ((size_t)((b * 128 + mt) * 256 + ch)) * 32);
#pragma unroll
        for (int r = 0; r < 4; ++r)
            vp[quad * 4 + r] = pk2bf(acc[1][ot][r] + bias, acc[0][ot][r] + bias);
    }
}

// ---------------------------------------------------------------------------
// attention: R3's PROVEN version, verbatim. 512 thr = 2 key-groups x 4 waves,
// 64 queries/block, 64 keys/iter. Direct global V fragments.
// ---------------------------------------------------------------------------
__global__ __launch_bounds__(512, 2) void attention(
    const unsigned short* __restrict__ qws, const unsigned short* __restrict__ kws,
    const unsigned short* __restrict__ vws, const float* __restrict__ ef,
    const float* __restrict__ gamma, float* __restrict__ out)
{
    __shared__ unsigned short Plds[2][2][64 * 72];   // [g][buf][q][72]
    __shared__ float mrg[256][68];
    __shared__ float denl[2][64];

    int t = threadIdx.x;
    int g = t >> 8, tl = t & 255;
    int w = tl >> 6, lane = tl & 63, quad = lane >> 4, l15 = lane & 15;
    int b = blockIdx.x >> 6, m0 = (blockIdx.x & 63) << 6;

    const unsigned short* kbase = kws + (size_t)(b * NSP) * 32;
    const unsigned short* vbase = vws + (size_t)(b * 128) * 8192;

    bf16x8 qf = *(const bf16x8*)(qws + ((size_t)(b * NSP) + m0 + w * 16 + l15) * 32 + quad * 8);

    f32x4 zero = {0.f, 0.f, 0.f, 0.f};
    f32x4 acc[4][4];
#pragma unroll
    for (int i = 0; i < 4; ++i)
#pragma unroll
        for (int j = 0; j < 4; ++j) acc[i][j] = zero;
    float lp0 = 0.f, lp1 = 0.f, lp2 = 0.f, lp3 = 0.f;

    int tt0 = g * 64;   // first 32-key tile of this group
    bf16x8 kf[4];
#pragma unroll
    for (int j = 0; j < 4; ++j)
        kf[j] = *(const bf16x8*)(kbase + (size_t)((tt0 + (j >> 1)) * 32 + (j & 1) * 16 + l15) * 32 + quad * 8);
    bf16x8 vf[2][4];
#pragma unroll
    for (int h = 0; h < 2; ++h)
#pragma unroll
        for (int cc = 0; cc < 4; ++cc)
            vf[h][cc] = *(const bf16x8*)(vbase + (size_t)(tt0 + h) * 8192 + (w * 64 + cc * 16 + l15) * 32 + quad * 8);

    for (int it = 0; it < 32; ++it) {
        int buf = it & 1;
        f32x4 s0 = MFMA16(qf, kf[0], zero);
        f32x4 s1 = MFMA16(qf, kf[1], zero);
        f32x4 s2 = MFMA16(qf, kf[2], zero);
        f32x4 s3 = MFMA16(qf, kf[3], zero);

        float e0[4], e1[4], e2[4], e3[4];
#pragma unroll
        for (int r = 0; r < 4; ++r) {
            e0[r] = __builtin_amdgcn_exp2f(s0[r]);
            e1[r] = __builtin_amdgcn_exp2f(s1[r]);
            e2[r] = __builtin_amdgcn_exp2f(s2[r]);
            e3[r] = __builtin_amdgcn_exp2f(s3[r]);
        }
        lp0 += (e0[0] + e1[0]) + (e2[0] + e3[0]);
        lp1 += (e0[1] + e1[1]) + (e2[1] + e3[1]);
        lp2 += (e0[2] + e1[2]) + (e2[2] + e3[2]);
        lp3 += (e0[3] + e1[3]) + (e2[3] + e3[3]);

        unsigned short* pd = &Plds[g][buf][(w * 16 + quad * 4) * 72 + 2 * l15];
#pragma unroll
        for (int r = 0; r < 4; ++r) {
            *(unsigned*)(pd + r * 72)      = pk2bf(e1[r], e0[r]);
            *(unsigned*)(pd + r * 72 + 32) = pk2bf(e3[r], e2[r]);
        }

        // prefetch next iteration
        int itn = it + 1 < 32 ? it + 1 : 31;
        int ttn = tt0 + 2 * itn;
#pragma unroll
        for (int j = 0; j < 4; ++j)
            kf[j] = *(const bf16x8*)(kbase + (size_t)((ttn + (j >> 1)) * 32 + (j & 1) * 16 + l15) * 32 + quad * 8);
        bf16x8 vfn[2][4];
#pragma unroll
        for (int h = 0; h < 2; ++h)
#pragma unroll
            for (int cc = 0; cc < 4; ++cc)
                vfn[h][cc] = *(const bf16x8*)(vbase + (size_t)(ttn + h) * 8192 + (w * 64 + cc * 16 + l15) * 32 + quad * 8);

        __syncthreads();

#pragma unroll
        for (int h = 0; h < 2; ++h) {
            bf16x8 pa0 = *(const bf16x8*)&Plds[g][buf][(0  + l15) * 72 + h * 32 + quad * 8];
            bf16x8 pa1 = *(const bf16x8*)&Plds[g][buf][(16 + l15) * 72 + h * 32 + quad * 8];
            bf16x8 pa2 = *(const bf16x8*)&Plds[g][buf][(32 + l15) * 72 + h * 32 + quad * 8];
            bf16x8 pa3 = *(const bf16x8*)&Plds[g][buf][(48 + l15) * 72 + h * 32 + quad * 8];
#pragma unroll
            for (int cc = 0; cc < 4; ++cc) {
                acc[0][cc] = MFMA16(pa0, vf[h][cc], acc[0][cc]);
                acc[1][cc] = MFMA16(pa1, vf[h][cc], acc[1][cc]);
                acc[2][cc] = MFMA16(pa2, vf[h][cc], acc[2][cc]);
                acc[3][cc] = MFMA16(pa3, vf[h][cc], acc[3][cc]);
            }
        }
#pragma unroll
        for (int h = 0; h < 2; ++h)
#pragma unroll
            for (int cc = 0; cc < 4; ++cc) vf[h][cc] = vfn[h][cc];
    }

    // per-group denominator partials
    lp0 += __shfl_xor(lp0, 1); lp0 += __shfl_xor(lp0, 2); lp0 += __shfl_xor(lp0, 4); lp0 += __shfl_xor(lp0, 8);
    lp1 += __shfl_xor(lp1, 1); lp1 += __shfl_xor(lp1, 2); lp1 += __shfl_xor(lp1, 4); lp1 += __shfl_xor(lp1, 8);
    lp2 += __shfl_xor(lp2, 1); lp2 += __shfl_xor(lp2, 2); lp2 += __shfl_xor(lp2, 4); lp2 += __shfl_xor(lp2, 8);
    lp3 += __shfl_xor(lp3, 1); lp3 += __shfl_xor(lp3, 2); lp3 += __shfl_xor(lp3, 4); lp3 += __shfl_xor(lp3, 8);
    if (l15 == 0) {
        int base = w * 16 + quad * 4;
        denl[g][base + 0] = lp0; denl[g][base + 1] = lp1;
        denl[g][base + 2] = lp2; denl[g][base + 3] = lp3;
    }
    if (g == 1) {
#pragma unroll
        for (int qc = 0; qc < 4; ++qc)
#pragma unroll
            for (int cc = 0; cc < 4; ++cc)
                *(f32x4*)&mrg[w * 64 + cc * 16 + l15][qc * 16 + quad * 4] = acc[qc][cc];
    }
    __syncthreads();

    if (g == 0) {
        float gam = gamma[0];
#pragma unroll
        for (int qc = 0; qc < 4; ++qc) {
            int qb = qc * 16 + quad * 4;
            float4 d0 = *(const float4*)&denl[0][qb];
            float4 d1 = *(const float4*)&denl[1][qb];
            float r0 = gam / (d0.x + d1.x), r1 = gam / (d0.y + d1.y);
            float r2 = gam / (d0.z + d1.z), r3 = gam / (d0.w + d1.w);
#pragma unroll
            for (int cc = 0; cc < 4; ++cc) {
                int ch = w * 64 + cc * 16 + l15;
                f32x4 part = *(const f32x4*)&mrg[ch][qb];
                size_t off = ((size_t)(b * NC + ch)) * NSP + m0 + qb;
                float4 e = *(const float4*)(ef + off);
                float4 o;
                o.x = (acc[qc][cc][0] + part[0]) * r0 + e.x;
                o.y = (acc[qc][cc][1] + part[1]) * r1 + e.y;
                o.z = (acc[qc][cc][2] + part[2]) * r2 + e.z;
                o.w = (acc[qc][cc][3] + part[3]) * r3 + e.w;
                *(float4*)(out + off) = o;
            }
        }
    }
}

// ---------------------------------------------------------------------------
extern "C" void kernel_launch(void* const* d_in, const int* in_sizes, int n_in,
                              void* d_out, int out_size, void* d_ws, size_t ws_size,
                              hipStream_t stream) {
    const float* ef    = (const float*)d_in[0];
    const float* sf    = (const float*)d_in[1];
    const float* attn  = (const float*)d_in[2];
    const float* Qw    = (const float*)d_in[3];
    const float* Qb    = (const float*)d_in[4];
    const float* Kw    = (const float*)d_in[5];
    const float* Kb    = (const float*)d_in[6];
    const float* Vw    = (const float*)d_in[7];
    const float* Vb    = (const float*)d_in[8];
    const float* gamma = (const float*)d_in[9];
    float* out = (float*)d_out;

    // workspace carve (~10.8 MB)
    unsigned short* qws  = (unsigned short*)d_ws;                    // 4*4096*32
    unsigned short* kws  = qws + (size_t)4 * 4096 * 32;              // 4*4096*32
    unsigned short* vws  = kws + (size_t)4 * 4096 * 32;              // 4*128*256*32
    unsigned short* Qwbf = vws + (size_t)4 * 128 * 256 * 32;         // 32*512
    unsigned short* Kwbf = Qwbf + 32 * 512;                          // 32*256
    unsigned short* Vwbf = Kwbf + 32 * 256;                          // 256*512

    hipLaunchKernelGGL(prep_w, dim3(64), dim3(256), 0, stream,
                       Qw, Kw, Vw, Qwbf, Kwbf, Vwbf);
    hipLaunchKernelGGL(proj_q, dim3(128, 4), dim3(256), 0, stream,
                       ef, sf, Qwbf, Qb, qws);
    hipLaunchKernelGGL(proj_k, dim3(128, 4), dim3(256), 0, stream,
                       attn, Kwbf, Kb, kws);
    hipLaunchKernelGGL(proj_v, dim3(128, 4), dim3(256), 0, stream,
                       ef, sf, Vwbf, Vb, vws);
    hipLaunchKernelGGL(attention, dim3(256), dim3(512), 0, stream,
                       qws, kws, vws, ef, gamma, out);
}